// Round 7
// baseline (261.013 us; speedup 1.0000x reference)
//
#include <hip/hip_runtime.h>
#include <hip/hip_bf16.h>
#include <math.h>

// Problem constants (match reference setup_inputs)
#define NN 4096
#define MM 128
#define QQ 64
#define DD 128
#define CC (MM * QQ)          // 8192 gemm "columns" (flattened m,q)

typedef short bf16x8 __attribute__((ext_vector_type(8)));  // 8 bf16 = 4 VGPRs
typedef float f32x4  __attribute__((ext_vector_type(4)));

static __device__ inline unsigned short f2bf(float f) {
    __hip_bfloat16 h = __float2bfloat16(f);
    return *reinterpret_cast<unsigned short*>(&h);
}

// Grid barrier: works because ALL 512 blocks are co-resident (2/CU x 256 CU,
// guaranteed by __launch_bounds__(512,4): VGPR<=128 -> 4 waves/SIMD, LDS 66KB<=80KB).
// Release: __syncthreads drains vmcnt (stores in L2), __threadfence writes back L2.
// Acquire: __threadfence after spin invalidates local caches.
static __device__ inline void grid_sync(unsigned int* cnt, unsigned int target) {
    __syncthreads();
    if (threadIdx.x == 0) {
        __threadfence();
        atomicAdd(cnt, 1u);
        while (atomicAdd(cnt, 0u) < target) __builtin_amdgcn_s_sleep(1);
    }
    __syncthreads();
    __threadfence();
}

// ---- single fused kernel: prep -> dens (MFMA) -> normalize ----
__global__ __launch_bounds__(512, 4)
void kde_mono_kernel(const float* __restrict__ A,   // [NN][DD] fp32
                     const float* __restrict__ B,   // [CC][DD] fp32
                     const float* __restrict__ var,
                     unsigned short* __restrict__ Abf,
                     unsigned short* __restrict__ Bbf,
                     float* __restrict__ a2w, float* __restrict__ b2w,
                     float* __restrict__ dpc,       // [MM][NN] transposed dens
                     unsigned int* __restrict__ cnt,
                     float* __restrict__ out)       // [NN][MM]
{
    __shared__ unsigned short TA[128 * DD];   // 32 KB (phase 3 reuses as float*)
    __shared__ unsigned short TB[128 * DD];   // 32 KB
    __shared__ float a2s[128];
    __shared__ float b2s[128];
    __shared__ float red[8][32];
    __shared__ float den3[8];

    const int t = threadIdx.x;
    const int b = blockIdx.x;                 // 0..511

    // ================= phase 1: fp32->bf16 + squared norms (24 rows/block) ====
    {
        const int l32 = t & 31;
        #pragma unroll
        for (int it = 0; it < 2; ++it) {
            const int lr = it * 16 + (t >> 5);       // 0..15 then 16..31
            if (lr < 24) {
                const int row = b * 24 + lr;          // 0..12287
                const float* src; unsigned short* dst; float* nrm;
                if (row < NN) { src = A + (size_t)row * DD; dst = Abf + (size_t)row * DD; nrm = a2w + row; }
                else { int r = row - NN; src = B + (size_t)r * DD; dst = Bbf + (size_t)r * DD; nrm = b2w + r; }
                float4 v = ((const float4*)src)[l32];
                ushort4 u;
                u.x = f2bf(v.x); u.y = f2bf(v.y); u.z = f2bf(v.z); u.w = f2bf(v.w);
                ((ushort4*)dst)[l32] = u;
                float s = v.x * v.x + v.y * v.y + v.z * v.z + v.w * v.w;
                #pragma unroll
                for (int mk = 16; mk; mk >>= 1) s += __shfl_xor(s, mk, 64);
                if (l32 == 0) *nrm = s;
            }
        }
    }
    grid_sync(cnt, 512);

    // ================= phase 2: bf16 MFMA dens, B-tile staged once, 4 n-tiles ====
    const int w = t >> 6, lane = t & 63, l15 = lane & 15, q = lane >> 4;
    const int xcd = b & 7, j = b >> 3;
    const int cb  = (xcd << 3) | (j & 7);     // 0..63  (XCD-local c block)
    const int nb0 = j >> 3;                   // 0..7
    const int c0  = cb * 128;
    const float hinv = 0.5f / var[0];

    {   // stage B tile (128 rows) once, XOR chunk swizzle (cb16 ^= row&7)
        const unsigned short* Bb = Bbf + (size_t)c0 * DD;
        #pragma unroll
        for (int i = 0; i < 4; ++i) {
            const int slot = w * 256 + i * 64 + lane;     // 0..2047
            const int r = slot >> 4, c16 = slot & 15, scb = c16 ^ (r & 7);
            const unsigned short* g = Bb + r * DD + scb * 8;
            unsigned short* lbase = &TB[(w * 256 + i * 64) * 8];
            __builtin_amdgcn_global_load_lds(
                (const __attribute__((address_space(1))) unsigned int*)g,
                (__attribute__((address_space(3))) unsigned int*)lbase, 16, 0, 0);
        }
        if (t >= 128 && t < 256) b2s[t - 128] = b2w[c0 + (t - 128)];
    }

    const int rbase = (w & 3) * 32, cbase = (w >> 2) * 64, xr = l15 & 7;
    const int m = cb * 2 + (w >> 2);

    for (int itn = 0; itn < 4; ++itn) {
        const int n0 = (nb0 + itn * 8) * 128;
        if (itn) __syncthreads();             // prior readers of TA done
        {   // stage A tile for this n0
            const unsigned short* Ab = Abf + (size_t)n0 * DD;
            #pragma unroll
            for (int i = 0; i < 4; ++i) {
                const int slot = w * 256 + i * 64 + lane;
                const int r = slot >> 4, c16 = slot & 15, scb = c16 ^ (r & 7);
                const unsigned short* g = Ab + r * DD + scb * 8;
                unsigned short* lbase = &TA[(w * 256 + i * 64) * 8];
                __builtin_amdgcn_global_load_lds(
                    (const __attribute__((address_space(1))) unsigned int*)g,
                    (__attribute__((address_space(3))) unsigned int*)lbase, 16, 0, 0);
            }
            if (t < 128) a2s[t] = a2w[n0 + t];
        }
        __syncthreads();                      // drains vmcnt (A DMA; B DMA on itn=0)

        f32x4 acc[2][4] = {};
        #pragma unroll
        for (int ks = 0; ks < 4; ++ks) {      // K = 4 * 32
            const int off = ((ks * 4 + q) ^ xr) * 8;
            bf16x8 af[2], bf[4];
            #pragma unroll
            for (int i = 0; i < 2; ++i)
                af[i] = *(const bf16x8*)&TA[(rbase + i * 16 + l15) * DD + off];
            #pragma unroll
            for (int jj = 0; jj < 4; ++jj)
                bf[jj] = *(const bf16x8*)&TB[(cbase + jj * 16 + l15) * DD + off];
            #pragma unroll
            for (int i = 0; i < 2; ++i)
                #pragma unroll
                for (int jj = 0; jj < 4; ++jj)
                    acc[i][jj] = __builtin_amdgcn_mfma_f32_16x16x32_bf16(
                                     af[i], bf[jj], acc[i][jj], 0, 0, 0);
        }

        // epilogue: exp + sum over the wave's 64 cols (= one m)
        float rowsum[2][4];
        #pragma unroll
        for (int i = 0; i < 2; ++i) {
            #pragma unroll
            for (int reg = 0; reg < 4; ++reg) {
                const float a2 = a2s[rbase + i * 16 + q * 4 + reg];
                float p = 0.f;
                #pragma unroll
                for (int jj = 0; jj < 4; ++jj) {
                    const float b2 = b2s[cbase + jj * 16 + l15];
                    p += __expf((2.f * acc[i][jj][reg] - a2 - b2) * hinv);
                }
                rowsum[i][reg] = p;
            }
        }
        #pragma unroll
        for (int mask = 1; mask < 16; mask <<= 1)
            #pragma unroll
            for (int i = 0; i < 2; ++i)
                #pragma unroll
                for (int reg = 0; reg < 4; ++reg)
                    rowsum[i][reg] += __shfl_xor(rowsum[i][reg], mask, 64);

        if (l15 == 0) {
            #pragma unroll
            for (int i = 0; i < 2; ++i)
                #pragma unroll
                for (int reg = 0; reg < 4; ++reg)
                    red[w][i * 16 + q * 4 + reg] = rowsum[i][reg];
        }
        // wave-private LDS region: compiler lgkmcnt orders this, no barrier needed
        if (lane < 32)
            dpc[(size_t)m * NN + n0 + rbase + lane] = red[w][lane];
    }
    grid_sync(cnt, 1024);

    // ================= phase 3: normalize 8 n-rows/block ====
    {
        float* ftab = (float*)TA;             // [128 m][stride 9]
        const int n0 = b * 8;
        if (t < 256) {
            const int mr = t >> 1, half = t & 1;
            float4 v = *(const float4*)&dpc[(size_t)mr * NN + n0 + half * 4];
            float* d = &ftab[mr * 9 + half * 4];
            d[0] = v.x; d[1] = v.y; d[2] = v.z; d[3] = v.w;
        }
        __syncthreads();
        if (t < 8) {
            float s = 0.f;
            #pragma unroll 8
            for (int mr = 0; mr < MM; ++mr) s += ftab[mr * 9 + t];
            den3[t] = 1.f / (s + 1e-10f);
        }
        __syncthreads();
        const int nloc = t >> 6, m0 = (t & 63) * 2;
        const float r = den3[nloc];
        float2 o;
        o.x = ftab[m0 * 9 + nloc] * r;
        o.y = ftab[(m0 + 1) * 9 + nloc] * r;
        *(float2*)&out[(size_t)(n0 + nloc) * MM + m0] = o;
    }
}

extern "C" void kernel_launch(void* const* d_in, const int* in_sizes, int n_in,
                              void* d_out, int out_size, void* d_ws, size_t ws_size,
                              hipStream_t stream) {
    const float* A   = (const float*)d_in[0];   // [4096][128]
    const float* B   = (const float*)d_in[1];   // [128][64][128] = [8192][128]
    const float* var = (const float*)d_in[2];   // [1]
    float* out = (float*)d_out;                 // [4096][128]

    char* ws = (char*)d_ws;
    unsigned short* Abf = (unsigned short*)(ws);               // 1 MB
    unsigned short* Bbf = (unsigned short*)(ws + (1u << 20));  // 2 MB
    float* a2  = (float*)(ws + (3u << 20));                    // 16 KB
    float* b2  = (float*)(ws + (3u << 20) + (1u << 16));       // 32 KB
    float* dpc = (float*)(ws + (4u << 20));                    // 2 MB [MM][NN]
    unsigned int* cnt = (unsigned int*)(ws + (8u << 20));      // 4 B barrier counter

    hipMemsetAsync(cnt, 0, sizeof(unsigned int), stream);
    kde_mono_kernel<<<512, 512, 0, stream>>>(A, B, var, Abf, Bbf, a2, b2, dpc, cnt, out);
}

// Round 8
// 105.144 us; speedup vs baseline: 2.4824x; 2.4824x over previous
//
#include <hip/hip_runtime.h>
#include <hip/hip_bf16.h>
#include <math.h>

// Problem constants (match reference setup_inputs)
#define NN 4096
#define MM 128
#define QQ 64
#define DD 128
#define CC (MM * QQ)          // 8192 gemm "columns" (flattened m,q)

typedef short bf16x8 __attribute__((ext_vector_type(8)));  // 8 bf16 = 4 VGPRs
typedef float f32x4  __attribute__((ext_vector_type(4)));

#define LDA 136               // padded LDS row stride (ushorts); 272B -> chunk stride 17 (==1 mod 8)

static __device__ inline unsigned short f2bf_trunc(float f) {
    union { float f; unsigned int u; } c; c.f = f;
    return (unsigned short)(c.u >> 16);   // truncate: 1 VALU op; fine in underflow regime
}

// ---- main: fused convert + bf16 MFMA (one-shot K=128), 128n x 128c (= 2 m) per block ----
// Stages fp32 tiles global->VGPR, converts to bf16, ds_writes padded LDS; computes
// exact fp32 row norms in-block during staging. 64KB tile LDS + 1.2KB -> 2 blocks/CU.
// dens written transposed: dpc[m][n].
__global__ __launch_bounds__(512, 4)
void kde_dens_kernel(const float* __restrict__ A,   // [NN][DD] fp32
                     const float* __restrict__ B,   // [CC][DD] fp32
                     const float* __restrict__ var,
                     float* __restrict__ dpc)       // [MM][NN] transposed
{
    __shared__ unsigned short As[128 * LDA];   // 34 KB
    __shared__ unsigned short Bs[128 * LDA];   // 34 KB  (total 68 KB + small)
    __shared__ float a2s[128];
    __shared__ float b2s[128];
    __shared__ float red[8][32];

    // XCD swizzle: XCD x owns cb in [8x, 8x+8) -> per-XCD fp32 slab A 2MB + B 512KB (L2-fit)
    const int lin = blockIdx.x;                 // 0..2047
    const int xcd = lin & 7;
    const int loc = lin >> 3;                   // 0..255
    const int cb  = (xcd << 3) | (loc & 7);     // 0..63
    const int nb  = loc >> 3;                   // 0..31
    const int n0  = nb * 128;
    const int c0  = cb * 128;

    const int t   = threadIdx.x;                // 0..511
    const int l32 = t & 31;                     // lane-in-half-wave
    const int rr  = t >> 5;                     // 0..15: row group

    // ---- staging: half-wave per row; load fp32 float4, cvt, ds_write, norm ----
    #pragma unroll
    for (int it = 0; it < 8; ++it) {
        const int row = it * 16 + rr;           // 0..127
        // A row
        {
            float4 v = *(const float4*)&A[(size_t)(n0 + row) * DD + l32 * 4];
            ushort4 u;
            u.x = f2bf_trunc(v.x); u.y = f2bf_trunc(v.y);
            u.z = f2bf_trunc(v.z); u.w = f2bf_trunc(v.w);
            *(ushort4*)&As[row * LDA + l32 * 4] = u;
            float s = v.x * v.x + v.y * v.y + v.z * v.z + v.w * v.w;
            #pragma unroll
            for (int mk = 16; mk; mk >>= 1) s += __shfl_xor(s, mk, 64); // stays in 32-group
            if (l32 == 0) a2s[row] = s;
        }
        // B row
        {
            float4 v = *(const float4*)&B[(size_t)(c0 + row) * DD + l32 * 4];
            ushort4 u;
            u.x = f2bf_trunc(v.x); u.y = f2bf_trunc(v.y);
            u.z = f2bf_trunc(v.z); u.w = f2bf_trunc(v.w);
            *(ushort4*)&Bs[row * LDA + l32 * 4] = u;
            float s = v.x * v.x + v.y * v.y + v.z * v.z + v.w * v.w;
            #pragma unroll
            for (int mk = 16; mk; mk >>= 1) s += __shfl_xor(s, mk, 64);
            if (l32 == 0) b2s[row] = s;
        }
    }
    __syncthreads();

    // ---- MFMA: wave w -> rows (w&3)*32, cols (w>>2)*64 (one m per wave) ----
    const int w = t >> 6, lane = t & 63, l15 = lane & 15, q = lane >> 4;
    const int rbase = (w & 3) * 32, cbase = (w >> 2) * 64;

    f32x4 acc[2][4] = {};
    #pragma unroll
    for (int ks = 0; ks < 4; ++ks) {            // K = 4 * 32
        const int off = ks * 32 + q * 8;
        bf16x8 af[2], bf[4];
        #pragma unroll
        for (int i = 0; i < 2; ++i)
            af[i] = *(const bf16x8*)&As[(rbase + i * 16 + l15) * LDA + off];
        #pragma unroll
        for (int j = 0; j < 4; ++j)
            bf[j] = *(const bf16x8*)&Bs[(cbase + j * 16 + l15) * LDA + off];
        #pragma unroll
        for (int i = 0; i < 2; ++i)
            #pragma unroll
            for (int j = 0; j < 4; ++j)
                acc[i][j] = __builtin_amdgcn_mfma_f32_16x16x32_bf16(
                                af[i], bf[j], acc[i][j], 0, 0, 0);
    }

    // ---- epilogue: exp + sum over the wave's 64 cols (= one m) ----
    const float hinv = 0.5f / var[0];
    float rowsum[2][4];
    #pragma unroll
    for (int i = 0; i < 2; ++i) {
        #pragma unroll
        for (int reg = 0; reg < 4; ++reg) {
            const float a2 = a2s[rbase + i * 16 + q * 4 + reg];
            float p = 0.f;
            #pragma unroll
            for (int j = 0; j < 4; ++j) {
                const float b2 = b2s[cbase + j * 16 + l15];
                p += __expf((2.f * acc[i][j][reg] - a2 - b2) * hinv);
            }
            rowsum[i][reg] = p;
        }
    }
    #pragma unroll
    for (int mask = 1; mask < 16; mask <<= 1)
        #pragma unroll
        for (int i = 0; i < 2; ++i)
            #pragma unroll
            for (int reg = 0; reg < 4; ++reg)
                rowsum[i][reg] += __shfl_xor(rowsum[i][reg], mask, 64);

    // coalesce via wave-private LDS slot (in-order LDS pipe, no barrier needed)
    if (l15 == 0) {
        #pragma unroll
        for (int i = 0; i < 2; ++i)
            #pragma unroll
            for (int reg = 0; reg < 4; ++reg)
                red[w][i * 16 + q * 4 + reg] = rowsum[i][reg];
    }
    const int m = (cb << 1) + (w >> 2);
    if (lane < 32)
        dpc[(size_t)m * NN + n0 + rbase + lane] = red[w][lane];
}

// ---- normalize: out[n,m] = dpc[m,n] / (sum_m dpc[:,n] + 1e-10), coalesced ----
__global__ __launch_bounds__(1024)
void kde_norm_kernel(const float* __restrict__ dpc, float* __restrict__ out)
{
    __shared__ float tile[MM][65];     // [m][nloc], odd stride
    __shared__ float rden[64];
    const int n0 = blockIdx.x * 64;
    const int t  = threadIdx.x;

    // stage 128 m x 64 n slab, coalesced float4 reads
    #pragma unroll
    for (int it = 0; it < 2; ++it) {
        const int m  = (t >> 4) + it * 64;
        const int nc = (t & 15) * 4;
        float4 v = *(const float4*)&dpc[(size_t)m * NN + n0 + nc];
        tile[m][nc]     = v.x;
        tile[m][nc + 1] = v.y;
        tile[m][nc + 2] = v.z;
        tile[m][nc + 3] = v.w;
    }
    __syncthreads();

    if (t < 64) {
        float s = 0.f;
        #pragma unroll 8
        for (int m = 0; m < MM; ++m) s += tile[m][t];
        rden[t] = 1.f / (s + 1e-10f);
    }
    __syncthreads();

    // write out[n][m], coalesced: thread covers 8 consecutive m of one n-row
    const int nloc = t >> 4;
    const int m0   = (t & 15) * 8;
    const float r  = rden[nloc];
    float4 o0, o1;
    o0.x = tile[m0][nloc] * r;     o0.y = tile[m0 + 1][nloc] * r;
    o0.z = tile[m0 + 2][nloc] * r; o0.w = tile[m0 + 3][nloc] * r;
    o1.x = tile[m0 + 4][nloc] * r; o1.y = tile[m0 + 5][nloc] * r;
    o1.z = tile[m0 + 6][nloc] * r; o1.w = tile[m0 + 7][nloc] * r;
    float* obase = &out[(size_t)(n0 + nloc) * MM + m0];
    *(float4*)obase       = o0;
    *(float4*)(obase + 4) = o1;
}

extern "C" void kernel_launch(void* const* d_in, const int* in_sizes, int n_in,
                              void* d_out, int out_size, void* d_ws, size_t ws_size,
                              hipStream_t stream) {
    const float* A   = (const float*)d_in[0];   // [4096][128]
    const float* B   = (const float*)d_in[1];   // [128][64][128] = [8192][128]
    const float* var = (const float*)d_in[2];   // [1]
    float* out = (float*)d_out;                 // [4096][128]
    float* dpc = (float*)d_ws;                  // 2 MB, [MM][NN] transposed

    kde_dens_kernel<<<2048, 512, 0, stream>>>(A, B, var, dpc);
    kde_norm_kernel<<<NN / 64, 1024, 0, stream>>>(dpc, out);
}

// Round 9
// 87.836 us; speedup vs baseline: 2.9716x; 1.1970x over previous
//
#include <hip/hip_runtime.h>
#include <hip/hip_bf16.h>
#include <math.h>

// Problem constants (match reference setup_inputs)
#define NN 4096
#define MM 128
#define QQ 64
#define DD 128
#define CC (MM * QQ)          // 8192 gemm "columns" (flattened m,q)

typedef short bf16x8 __attribute__((ext_vector_type(8)));  // 8 bf16 = 4 VGPRs
typedef float f32x4  __attribute__((ext_vector_type(4)));

#define AS1 __attribute__((address_space(1)))
#define AS3 __attribute__((address_space(3)))

static __device__ inline unsigned short f2bf(float f) {
    __hip_bfloat16 h = __float2bfloat16(f);
    return *reinterpret_cast<unsigned short*>(&h);
}

// ---- prep: fp32->bf16 convert + exact fp32 squared norms, float4 loads ----
__global__ __launch_bounds__(256)
void prep_kernel(const float* __restrict__ A, const float* __restrict__ B,
                 unsigned short* __restrict__ Abf, unsigned short* __restrict__ Bbf,
                 float* __restrict__ a2, float* __restrict__ b2)
{
    const int row = blockIdx.x * 8 + (threadIdx.x >> 5);    // 0..12287
    const int l32 = threadIdx.x & 31;
    const float* src;
    unsigned short* dst;
    float* nrm;
    if (row < NN) { src = A + (size_t)row * DD; dst = Abf + (size_t)row * DD; nrm = a2 + row; }
    else {
        int r = row - NN;
        src = B + (size_t)r * DD; dst = Bbf + (size_t)r * DD; nrm = b2 + r;
    }
    float4 v = ((const float4*)src)[l32];
    ushort4 u;
    u.x = f2bf(v.x); u.y = f2bf(v.y); u.z = f2bf(v.z); u.w = f2bf(v.w);
    ((ushort4*)dst)[l32] = u;
    float s = v.x * v.x + v.y * v.y + v.z * v.z + v.w * v.w;
    #pragma unroll
    for (int m = 16; m > 0; m >>= 1) s += __shfl_xor(s, m, 64);  // stays in 32-group
    if (l32 == 0) *nrm = s;
}

// ---- dens: persistent A-panel + double-buffered B-tile c-loop ----
// Grid 256 = 8 XCD x 32 n-panels, 1024 threads (16 waves), 1 block/CU (LDS 97KB).
// Block: A panel 128 n-rows staged once (DMA, XOR chunk swizzle); loop 8 B-tiles
// (128 c = 2 m) of its XCD slab: prefetch(it+1) -> compute(it) -> barrier.
// Wave w: rows (w&7)*16, col-half (w>>3)*64 (= one m). dpc transposed [m][n].
__global__ __launch_bounds__(1024, 4)
void kde_dens_kernel(const unsigned short* __restrict__ Abf,  // [NN][DD] bf16
                     const unsigned short* __restrict__ Bbf,  // [CC][DD] bf16
                     const float* __restrict__ var,
                     const float* __restrict__ a2w,           // [NN]
                     const float* __restrict__ b2w,           // [CC]
                     float* __restrict__ dpc)                 // [MM][NN] transposed
{
    __shared__ unsigned short As[128 * DD];      // 32 KB
    __shared__ unsigned short Bs[2][128 * DD];   // 64 KB
    __shared__ float a2s[128];
    __shared__ float b2s[2][128];

    const int b   = blockIdx.x;          // 0..255
    const int xcd = b & 7;
    const int nb  = b >> 3;              // 0..31
    const int n0  = nb * 128;

    const int t = threadIdx.x, w = t >> 6, lane = t & 63;

    // ---- stage A panel once: 2048 16B chunks, 2 per lane ----
    {
        const unsigned short* Ab = Abf + (size_t)n0 * DD;
        #pragma unroll
        for (int i = 0; i < 2; ++i) {
            const int slot = w * 128 + i * 64 + lane;      // 0..2047
            const int r = slot >> 4, c16 = slot & 15, scb = c16 ^ (r & 7);
            __builtin_amdgcn_global_load_lds(
                (const AS1 unsigned int*)(Ab + r * DD + scb * 8),
                (AS3 unsigned int*)&As[(w * 128 + i * 64) * 8], 16, 0, 0);
        }
        if (t < 128) a2s[t] = a2w[n0 + t];
    }
    // ---- stage B tile 0 ----
    {
        const int cb = (xcd << 3) | (nb & 7);
        const unsigned short* Bb = Bbf + (size_t)cb * 128 * DD;
        #pragma unroll
        for (int i = 0; i < 2; ++i) {
            const int slot = w * 128 + i * 64 + lane;
            const int r = slot >> 4, c16 = slot & 15, scb = c16 ^ (r & 7);
            __builtin_amdgcn_global_load_lds(
                (const AS1 unsigned int*)(Bb + r * DD + scb * 8),
                (AS3 unsigned int*)&Bs[0][(w * 128 + i * 64) * 8], 16, 0, 0);
        }
        if (t >= 128 && t < 256) b2s[0][t - 128] = b2w[cb * 128 + (t - 128)];
    }
    __syncthreads();            // drain A + B0 DMA

    const int l15 = lane & 15, q = lane >> 4, xr = l15 & 7;
    const int rbase = (w & 7) * 16;
    const int chalf = w >> 3;                  // 0/1: which m of the tile
    const int cbase = chalf * 64;
    const float hinv = 0.5f / var[0];

    for (int it = 0; it < 8; ++it) {
        const int cur = it & 1;
        const int cb  = (xcd << 3) | ((nb + it) & 7);

        // ---- prefetch next B tile into the other buffer (hidden by compute) ----
        if (it < 7) {
            const int cbn = (xcd << 3) | ((nb + it + 1) & 7);
            const unsigned short* Bb = Bbf + (size_t)cbn * 128 * DD;
            #pragma unroll
            for (int i = 0; i < 2; ++i) {
                const int slot = w * 128 + i * 64 + lane;
                const int r = slot >> 4, c16 = slot & 15, scb = c16 ^ (r & 7);
                __builtin_amdgcn_global_load_lds(
                    (const AS1 unsigned int*)(Bb + r * DD + scb * 8),
                    (AS3 unsigned int*)&Bs[1 - cur][(w * 128 + i * 64) * 8], 16, 0, 0);
            }
            if (t >= 128 && t < 256) b2s[1 - cur][t - 128] = b2w[cbn * 128 + (t - 128)];
        }

        // ---- MFMA on current tile: wave = 16 rows x 64 cols (one m) ----
        f32x4 acc[4] = {};
        #pragma unroll
        for (int ks = 0; ks < 4; ++ks) {       // K = 4 * 32
            const int off = ((ks * 4 + q) ^ xr) * 8;
            const bf16x8 af = *(const bf16x8*)&As[(rbase + l15) * DD + off];
            #pragma unroll
            for (int j = 0; j < 4; ++j) {
                const bf16x8 bf = *(const bf16x8*)&Bs[cur][(cbase + j * 16 + l15) * DD + off];
                acc[j] = __builtin_amdgcn_mfma_f32_16x16x32_bf16(af, bf, acc[j], 0, 0, 0);
            }
        }

        // ---- epilogue: exp + sum over the wave's 64 cols ----
        float rowsum[4];
        #pragma unroll
        for (int reg = 0; reg < 4; ++reg) {
            const float a2 = a2s[rbase + q * 4 + reg];
            float p = 0.f;
            #pragma unroll
            for (int j = 0; j < 4; ++j) {
                const float b2 = b2s[cur][cbase + j * 16 + l15];
                p += __expf((2.f * acc[j][reg] - a2 - b2) * hinv);
            }
            rowsum[reg] = p;
        }
        #pragma unroll
        for (int mask = 1; mask < 16; mask <<= 1)
            #pragma unroll
            for (int reg = 0; reg < 4; ++reg)
                rowsum[reg] += __shfl_xor(rowsum[reg], mask, 64);

        // C-layout rows q*4+reg are consecutive -> one float4 store per q-lane
        if (l15 == 0) {
            const int m = cb * 2 + chalf;
            f32x4 o = {rowsum[0], rowsum[1], rowsum[2], rowsum[3]};
            *(f32x4*)&dpc[(size_t)m * NN + n0 + rbase + q * 4] = o;
        }

        __syncthreads();   // drains prefetch DMA (overlapped) + guards buffer reuse
    }
}

// ---- normalize: out[n,m] = dpc[m,n] / (sum_m dpc[:,n] + 1e-10), coalesced ----
__global__ __launch_bounds__(1024)
void kde_norm_kernel(const float* __restrict__ dpc, float* __restrict__ out)
{
    __shared__ float tile[MM][65];     // [m][nloc], odd stride
    __shared__ float rden[64];
    const int n0 = blockIdx.x * 64;
    const int t  = threadIdx.x;

    #pragma unroll
    for (int it = 0; it < 2; ++it) {
        const int m  = (t >> 4) + it * 64;
        const int nc = (t & 15) * 4;
        float4 v = *(const float4*)&dpc[(size_t)m * NN + n0 + nc];
        tile[m][nc]     = v.x;
        tile[m][nc + 1] = v.y;
        tile[m][nc + 2] = v.z;
        tile[m][nc + 3] = v.w;
    }
    __syncthreads();

    if (t < 64) {
        float s = 0.f;
        #pragma unroll 8
        for (int m = 0; m < MM; ++m) s += tile[m][t];
        rden[t] = 1.f / (s + 1e-10f);
    }
    __syncthreads();

    const int nloc = t >> 4;
    const int m0   = (t & 15) * 8;
    const float r  = rden[nloc];
    float4 o0, o1;
    o0.x = tile[m0][nloc] * r;     o0.y = tile[m0 + 1][nloc] * r;
    o0.z = tile[m0 + 2][nloc] * r; o0.w = tile[m0 + 3][nloc] * r;
    o1.x = tile[m0 + 4][nloc] * r; o1.y = tile[m0 + 5][nloc] * r;
    o1.z = tile[m0 + 6][nloc] * r; o1.w = tile[m0 + 7][nloc] * r;
    float* obase = &out[(size_t)(n0 + nloc) * MM + m0];
    *(float4*)obase       = o0;
    *(float4*)(obase + 4) = o1;
}

extern "C" void kernel_launch(void* const* d_in, const int* in_sizes, int n_in,
                              void* d_out, int out_size, void* d_ws, size_t ws_size,
                              hipStream_t stream) {
    const float* A   = (const float*)d_in[0];   // [4096][128]
    const float* B   = (const float*)d_in[1];   // [128][64][128] = [8192][128]
    const float* var = (const float*)d_in[2];   // [1]
    float* out = (float*)d_out;                 // [4096][128]

    unsigned short* Abf = (unsigned short*)d_ws;        // 1 MB
    unsigned short* Bbf = Abf + (size_t)NN * DD;        // 2 MB
    float* a2  = (float*)(Bbf + (size_t)CC * DD);       // 16 KB
    float* b2  = a2 + NN;                               // 32 KB
    float* dpc = b2 + CC;                               // 2 MB, [MM][NN]

    prep_kernel<<<(NN + CC) / 8, 256, 0, stream>>>(A, B, Abf, Bbf, a2, b2);
    kde_dens_kernel<<<256, 1024, 0, stream>>>(Abf, Bbf, var, a2, b2, dpc);
    kde_norm_kernel<<<NN / 64, 1024, 0, stream>>>(dpc, out);
}

// Round 10
// 87.130 us; speedup vs baseline: 2.9957x; 1.0081x over previous
//
#include <hip/hip_runtime.h>
#include <hip/hip_bf16.h>
#include <math.h>

// Problem constants (match reference setup_inputs)
#define NN 4096
#define MM 128
#define QQ 64
#define DD 128
#define CC (MM * QQ)          // 8192 gemm "columns" (flattened m,q)

typedef short bf16x8 __attribute__((ext_vector_type(8)));  // 8 bf16 = 4 VGPRs
typedef float f32x4  __attribute__((ext_vector_type(4)));

#define AS1 __attribute__((address_space(1)))
#define AS3 __attribute__((address_space(3)))

static __device__ inline unsigned short f2bf(float f) {
    __hip_bfloat16 h = __float2bfloat16(f);
    return *reinterpret_cast<unsigned short*>(&h);
}

// ---- prep: fp32->bf16 convert + exact fp32 squared norms, float4 loads ----
__global__ __launch_bounds__(256)
void prep_kernel(const float* __restrict__ A, const float* __restrict__ B,
                 unsigned short* __restrict__ Abf, unsigned short* __restrict__ Bbf,
                 float* __restrict__ a2, float* __restrict__ b2)
{
    const int row = blockIdx.x * 8 + (threadIdx.x >> 5);    // 0..12287
    const int l32 = threadIdx.x & 31;
    const float* src;
    unsigned short* dst;
    float* nrm;
    if (row < NN) { src = A + (size_t)row * DD; dst = Abf + (size_t)row * DD; nrm = a2 + row; }
    else {
        int r = row - NN;
        src = B + (size_t)r * DD; dst = Bbf + (size_t)r * DD; nrm = b2 + r;
    }
    float4 v = ((const float4*)src)[l32];
    ushort4 u;
    u.x = f2bf(v.x); u.y = f2bf(v.y); u.z = f2bf(v.z); u.w = f2bf(v.w);
    ((ushort4*)dst)[l32] = u;
    float s = v.x * v.x + v.y * v.y + v.z * v.z + v.w * v.w;
    #pragma unroll
    for (int m = 16; m > 0; m >>= 1) s += __shfl_xor(s, m, 64);  // stays in 32-group
    if (l32 == 0) *nrm = s;
}

// ---- dens: persistent 1 block/CU, fine-grained vmcnt pipeline (no vmcnt(0) drain) ----
// Block b: A-panel n0=(b>>3)*128 (staged once), c-slab xcd=b&7: cols [xcd*1024, +1024)
// = 8 chunks of 128 c (2 m). B dbuf 2x32KB. Per chunk per wave EXACTLY 5 vmem ops
// (4 B-DMA + 1 redundant b2-DMA, all waves identical) -> s_waitcnt vmcnt(5) gates
// chunk t while t+1 flies. Raw s_barrier (inline asm, NO implicit drain).
// Wave w: rows (w>>1)*32, cols (w&1)*64 (= one m). dpc transposed [m][n].
__global__ __launch_bounds__(512, 2)
void kde_dens_kernel(const unsigned short* __restrict__ Abf,  // [NN][DD] bf16
                     const unsigned short* __restrict__ Bbf,  // [CC][DD] bf16
                     const float* __restrict__ var,
                     const float* __restrict__ a2w,           // [NN]
                     const float* __restrict__ b2w,           // [CC] (+512B pad ok)
                     float* __restrict__ dpc)                 // [MM][NN] transposed
{
    __shared__ unsigned short As[128 * DD];        // 32 KB
    __shared__ unsigned short Bs[2][128 * DD];     // 64 KB
    __shared__ float b2s[2][256];                  // 2 KB (only [0..128) used/chunk)

    const int b     = blockIdx.x;        // 0..255 (1 per CU)
    const int xcd   = b & 7;
    const int n0    = (b >> 3) * 128;    // 32 panels
    const int slab0 = xcd * 1024;        // c-slab base

    const int t  = threadIdx.x;
    const int w  = t >> 6, lane = t & 63;
    const int l15 = lane & 15, q = lane >> 4, xr = l15 & 7;
    const int rbase = (w >> 1) * 32;     // wave rows
    const int cbase = (w & 1) * 64;      // wave cols (= which m of the chunk)

    // ---- oldest vmem first: a2 regs (in-order retirement keeps vmcnt math valid) ----
    float a2v[2][4];
    #pragma unroll
    for (int i = 0; i < 2; ++i)
        #pragma unroll
        for (int r = 0; r < 4; ++r)
            a2v[i][r] = a2w[n0 + rbase + i * 16 + q * 4 + r];
    const float hinv = 0.5f / var[0];

    // ---- A panel DMA: 4 instrs/wave ----
    {
        const unsigned short* Ab = Abf + (size_t)n0 * DD;
        #pragma unroll
        for (int i = 0; i < 4; ++i) {
            const int slot = w * 256 + i * 64 + lane;    // 0..2047
            const int r = slot >> 4, c16 = slot & 15, scb = c16 ^ (r & 7);
            __builtin_amdgcn_global_load_lds(
                (const AS1 unsigned int*)(Ab + r * DD + scb * 8),
                (AS3 unsigned int*)&As[(w * 256 + i * 64) * 8], 16, 0, 0);
        }
    }

    // issue chunk ct into buffer ct&1: 4 B-DMA + 1 b2-DMA = 5 vmem ops per wave
    #define ISSUE(ct)                                                              \
    {                                                                              \
        const int c0 = slab0 + (ct) * 128;                                         \
        const unsigned short* Bb = Bbf + (size_t)c0 * DD;                          \
        unsigned short* Bdst = &Bs[(ct) & 1][0];                                   \
        _Pragma("unroll")                                                          \
        for (int i = 0; i < 4; ++i) {                                              \
            const int slot = w * 256 + i * 64 + lane;                              \
            const int r = slot >> 4, c16 = slot & 15, scb = c16 ^ (r & 7);         \
            __builtin_amdgcn_global_load_lds(                                      \
                (const AS1 unsigned int*)(Bb + r * DD + scb * 8),                  \
                (AS3 unsigned int*)&Bdst[(w * 256 + i * 64) * 8], 16, 0, 0);       \
        }                                                                          \
        __builtin_amdgcn_global_load_lds(                                          \
            (const AS1 unsigned int*)(b2w + c0 + lane * 4),                        \
            (AS3 unsigned int*)&b2s[(ct) & 1][0], 16, 0, 0);                       \
    }

    ISSUE(0);
    ISSUE(1);

    #pragma unroll
    for (int ct = 0; ct < 8; ++ct) {
        // chunk ct's 5 ops (+ everything older: A, a2) complete; ct+1's 5 may fly
        asm volatile("s_waitcnt vmcnt(5)" ::: "memory");
        asm volatile("s_barrier" ::: "memory");     // all waves' ct-writes visible

        const unsigned short* Bsc = &Bs[ct & 1][0];
        const float* b2c = &b2s[ct & 1][0];

        f32x4 acc[2][4] = {};
        #pragma unroll
        for (int ks = 0; ks < 4; ++ks) {            // K = 4 * 32
            const int off = ((ks * 4 + q) ^ xr) * 8;
            bf16x8 af[2], bf[4];
            #pragma unroll
            for (int i = 0; i < 2; ++i)
                af[i] = *(const bf16x8*)&As[(rbase + i * 16 + l15) * DD + off];
            #pragma unroll
            for (int j = 0; j < 4; ++j)
                bf[j] = *(const bf16x8*)&Bsc[(cbase + j * 16 + l15) * DD + off];
            #pragma unroll
            for (int i = 0; i < 2; ++i)
                #pragma unroll
                for (int j = 0; j < 4; ++j)
                    acc[i][j] = __builtin_amdgcn_mfma_f32_16x16x32_bf16(
                                    af[i], bf[j], acc[i][j], 0, 0, 0);
        }

        // epilogue: exp + sum over the wave's 64 cols (= one m)
        float rowsum[2][4];
        #pragma unroll
        for (int i = 0; i < 2; ++i) {
            #pragma unroll
            for (int reg = 0; reg < 4; ++reg) {
                float p = 0.f;
                #pragma unroll
                for (int j = 0; j < 4; ++j) {
                    const float b2 = b2c[cbase + j * 16 + l15];
                    p += __expf((2.f * acc[i][j][reg] - a2v[i][reg] - b2) * hinv);
                }
                rowsum[i][reg] = p;
            }
        }
        #pragma unroll
        for (int mask = 1; mask < 16; mask <<= 1)
            #pragma unroll
            for (int i = 0; i < 2; ++i)
                #pragma unroll
                for (int reg = 0; reg < 4; ++reg)
                    rowsum[i][reg] += __shfl_xor(rowsum[i][reg], mask, 64);

        if (l15 == 0) {
            const int m = xcd * 16 + ct * 2 + (w & 1);
            #pragma unroll
            for (int i = 0; i < 2; ++i) {
                f32x4 o = {rowsum[i][0], rowsum[i][1], rowsum[i][2], rowsum[i][3]};
                *(f32x4*)&dpc[(size_t)m * NN + n0 + rbase + i * 16 + q * 4] = o;
            }
        }

        asm volatile("s_barrier" ::: "memory");     // buffer-reuse guard (no drain)
        if (ct < 6) ISSUE(ct + 2);
    }
    #undef ISSUE
}

// ---- normalize: out[n,m] = dpc[m,n] / (sum_m dpc[:,n] + 1e-10), coalesced ----
__global__ __launch_bounds__(1024)
void kde_norm_kernel(const float* __restrict__ dpc, float* __restrict__ out)
{
    __shared__ float tile[MM][65];     // [m][nloc], odd stride
    __shared__ float rden[64];
    const int n0 = blockIdx.x * 64;
    const int t  = threadIdx.x;

    #pragma unroll
    for (int it = 0; it < 2; ++it) {
        const int m  = (t >> 4) + it * 64;
        const int nc = (t & 15) * 4;
        float4 v = *(const float4*)&dpc[(size_t)m * NN + n0 + nc];
        tile[m][nc]     = v.x;
        tile[m][nc + 1] = v.y;
        tile[m][nc + 2] = v.z;
        tile[m][nc + 3] = v.w;
    }
    __syncthreads();

    if (t < 64) {
        float s = 0.f;
        #pragma unroll 8
        for (int m = 0; m < MM; ++m) s += tile[m][t];
        rden[t] = 1.f / (s + 1e-10f);
    }
    __syncthreads();

    const int nloc = t >> 4;
    const int m0   = (t & 15) * 8;
    const float r  = rden[nloc];
    float4 o0, o1;
    o0.x = tile[m0][nloc] * r;     o0.y = tile[m0 + 1][nloc] * r;
    o0.z = tile[m0 + 2][nloc] * r; o0.w = tile[m0 + 3][nloc] * r;
    o1.x = tile[m0 + 4][nloc] * r; o1.y = tile[m0 + 5][nloc] * r;
    o1.z = tile[m0 + 6][nloc] * r; o1.w = tile[m0 + 7][nloc] * r;
    float* obase = &out[(size_t)(n0 + nloc) * MM + m0];
    *(float4*)obase       = o0;
    *(float4*)(obase + 4) = o1;
}

extern "C" void kernel_launch(void* const* d_in, const int* in_sizes, int n_in,
                              void* d_out, int out_size, void* d_ws, size_t ws_size,
                              hipStream_t stream) {
    const float* A   = (const float*)d_in[0];   // [4096][128]
    const float* B   = (const float*)d_in[1];   // [128][64][128] = [8192][128]
    const float* var = (const float*)d_in[2];   // [1]
    float* out = (float*)d_out;                 // [4096][128]

    unsigned short* Abf = (unsigned short*)d_ws;        // 1 MB
    unsigned short* Bbf = Abf + (size_t)NN * DD;        // 2 MB
    float* a2  = (float*)(Bbf + (size_t)CC * DD);       // 16 KB
    float* b2  = a2 + NN;                               // 32 KB (+ dpc after = pad)
    float* dpc = b2 + CC;                               // 2 MB, [MM][NN]

    prep_kernel<<<(NN + CC) / 8, 256, 0, stream>>>(A, B, Abf, Bbf, a2, b2);
    kde_dens_kernel<<<256, 512, 0, stream>>>(Abf, Bbf, var, a2, b2, dpc);
    kde_norm_kernel<<<NN / 64, 1024, 0, stream>>>(dpc, out);
}

// Round 11
// 78.718 us; speedup vs baseline: 3.3158x; 1.1069x over previous
//
#include <hip/hip_runtime.h>
#include <hip/hip_bf16.h>
#include <math.h>

// Problem constants (match reference setup_inputs)
#define NN 4096
#define MM 128
#define QQ 64
#define DD 128
#define CC (MM * QQ)          // 8192 gemm "columns" (flattened m,q)

typedef float f32x4 __attribute__((ext_vector_type(4)));
typedef int   i32x4 __attribute__((ext_vector_type(4)));
typedef int   i32x8 __attribute__((ext_vector_type(8)));

#define AS1 __attribute__((address_space(1)))
#define AS3 __attribute__((address_space(3)))

// ---- prep: fp32 -> fp8 e4m3 (OCP) convert + exact fp32 squared norms ----
// Half-wave (32 lanes) per row: float4 in, 4 fp8 bytes (one uint) out per lane.
__global__ __launch_bounds__(256)
void prep_kernel(const float* __restrict__ A, const float* __restrict__ B,
                 unsigned char* __restrict__ A8, unsigned char* __restrict__ B8,
                 float* __restrict__ a2, float* __restrict__ b2)
{
    const int row = blockIdx.x * 8 + (threadIdx.x >> 5);    // 0..12287
    const int l32 = threadIdx.x & 31;
    const float* src;
    unsigned char* dst;
    float* nrm;
    if (row < NN) { src = A + (size_t)row * DD; dst = A8 + (size_t)row * DD; nrm = a2 + row; }
    else {
        int r = row - NN;
        src = B + (size_t)r * DD; dst = B8 + (size_t)r * DD; nrm = b2 + r;
    }
    float4 v = ((const float4*)src)[l32];
    int pk = __builtin_amdgcn_cvt_pk_fp8_f32(v.x, v.y, 0, false);   // bytes 0,1
    pk     = __builtin_amdgcn_cvt_pk_fp8_f32(v.z, v.w, pk, true);   // bytes 2,3
    ((int*)dst)[l32] = pk;
    float s = v.x * v.x + v.y * v.y + v.z * v.z + v.w * v.w;
    #pragma unroll
    for (int m = 16; m > 0; m >>= 1) s += __shfl_xor(s, m, 64);  // stays in 32-group
    if (l32 == 0) *nrm = s;
}

// ---- dens: fp8 MX-scaled MFMA (K=128 in one instr), 128n x 128c (= 2 m)/block ----
// LDS: A8 16KB + B8 16KB (+1KB) -> 4 blocks/CU. DMA staging with XOR chunk swizzle
// (16B chunk cb stored at cb ^ (row&7); rows are 8 chunks). Frag reads: 2x b128
// per 16x16 frag (32B = whole K=128 per lane). Wave w of 8: rows (w&3)*32,
// cols (w>>2)*64 (one m). dens written transposed: dpc[m][n].
__global__ __launch_bounds__(512, 4)
void kde_dens_kernel(const unsigned char* __restrict__ A8,   // [NN][DD] fp8
                     const unsigned char* __restrict__ B8,   // [CC][DD] fp8
                     const float* __restrict__ var,
                     const float* __restrict__ a2w,          // [NN]
                     const float* __restrict__ b2w,          // [CC]
                     float* __restrict__ dpc)                // [MM][NN] transposed
{
    __shared__ unsigned char As[128 * DD];   // 16 KB
    __shared__ unsigned char Bs[128 * DD];   // 16 KB
    __shared__ float a2s[128];
    __shared__ float b2s[128];
    __shared__ float red[8][32];

    // XCD swizzle: XCD x owns cb in [8x, 8x+8)
    const int lin = blockIdx.x;                 // 0..2047
    const int xcd = lin & 7;
    const int loc = lin >> 3;                   // 0..255
    const int cb  = (xcd << 3) | (loc & 7);     // 0..63
    const int nb  = loc >> 3;                   // 0..31
    const int n0  = nb * 128;
    const int c0  = cb * 128;

    const int t = threadIdx.x, w = t >> 6, lane = t & 63;

    // ---- async staging: 1024 A-chunks + 1024 B-chunks (16 B), 2+2 instrs/wave ----
    {
        const unsigned char* Ab = A8 + (size_t)n0 * DD;
        const unsigned char* Bb = B8 + (size_t)c0 * DD;
        #pragma unroll
        for (int i = 0; i < 2; ++i) {
            const int slot = w * 128 + i * 64 + lane;   // 0..1023
            const int r = slot >> 3, c16 = slot & 7, scb = c16 ^ (r & 7);
            __builtin_amdgcn_global_load_lds(
                (const AS1 unsigned int*)(Ab + r * DD + scb * 16),
                (AS3 unsigned int*)&As[slot * 16], 16, 0, 0);
            __builtin_amdgcn_global_load_lds(
                (const AS1 unsigned int*)(Bb + r * DD + scb * 16),
                (AS3 unsigned int*)&Bs[slot * 16], 16, 0, 0);
        }
        if (t < 128)        a2s[t]       = a2w[n0 + t];
        else if (t < 256)   b2s[t - 128] = b2w[c0 + (t - 128)];
    }
    __syncthreads();   // drains vmcnt(0) incl. global_load_lds

    // ---- MFMA: wave w -> rows (w&3)*32, cols (w>>2)*64 (one m per wave) ----
    const int l15 = lane & 15, q = lane >> 4, xr = l15 & 7;
    const int rbase = (w & 3) * 32, cbase = (w >> 2) * 64;

    // A fragments: lane holds A[row rbase+i*16+l15][k q*32 .. q*32+31] (32 B)
    i32x8 a8[2];
    #pragma unroll
    for (int i = 0; i < 2; ++i) {
        const int ro = (rbase + i * 16 + l15) * DD;
        const i32x4 lo = *(const i32x4*)&As[ro + (((q << 1) | 0) ^ xr) * 16];
        const i32x4 hi = *(const i32x4*)&As[ro + (((q << 1) | 1) ^ xr) * 16];
        #pragma unroll
        for (int e = 0; e < 4; ++e) { a8[i][e] = lo[e]; a8[i][4 + e] = hi[e]; }
    }

    f32x4 acc[2][4] = {};
    #pragma unroll
    for (int j = 0; j < 4; ++j) {
        const int ro = (cbase + j * 16 + l15) * DD;
        const i32x4 lo = *(const i32x4*)&Bs[ro + (((q << 1) | 0) ^ xr) * 16];
        const i32x4 hi = *(const i32x4*)&Bs[ro + (((q << 1) | 1) ^ xr) * 16];
        i32x8 b8;
        #pragma unroll
        for (int e = 0; e < 4; ++e) { b8[e] = lo[e]; b8[4 + e] = hi[e]; }
        #pragma unroll
        for (int i = 0; i < 2; ++i)
            acc[i][j] = __builtin_amdgcn_mfma_scale_f32_16x16x128_f8f6f4(
                            a8[i], b8, acc[i][j],
                            0, 0,          // cbsz=0 (fp8 e4m3 A), blgp=0 (fp8 B)
                            0, 127,        // opsel_a, scale_a = E8M0 127 -> 1.0
                            0, 127);       // opsel_b, scale_b = 1.0
    }

    // ---- epilogue: dens = exp((2ab - a2 - b2) * 0.5/var); sum over 64 cols ----
    const float hinv = 0.5f / var[0];
    float rowsum[2][4];
    #pragma unroll
    for (int i = 0; i < 2; ++i) {
        #pragma unroll
        for (int reg = 0; reg < 4; ++reg) {
            const float a2 = a2s[rbase + i * 16 + q * 4 + reg];
            float p = 0.f;
            #pragma unroll
            for (int j = 0; j < 4; ++j) {
                const float b2 = b2s[cbase + j * 16 + l15];
                p += __expf((2.f * acc[i][j][reg] - a2 - b2) * hinv);
            }
            rowsum[i][reg] = p;
        }
    }
    #pragma unroll
    for (int mask = 1; mask < 16; mask <<= 1)
        #pragma unroll
        for (int i = 0; i < 2; ++i)
            #pragma unroll
            for (int reg = 0; reg < 4; ++reg)
                rowsum[i][reg] += __shfl_xor(rowsum[i][reg], mask, 64);

    // coalesce via wave-private LDS slot (in-order LDS pipe, no barrier needed)
    if (l15 == 0) {
        #pragma unroll
        for (int i = 0; i < 2; ++i)
            #pragma unroll
            for (int reg = 0; reg < 4; ++reg)
                red[w][i * 16 + q * 4 + reg] = rowsum[i][reg];
    }
    const int m = (cb << 1) + (w >> 2);
    if (lane < 32)
        dpc[(size_t)m * NN + n0 + (w & 3) * 32 + lane] = red[w][lane];
}

// ---- normalize: out[n,m] = dpc[m,n] / (sum_m dpc[:,n] + 1e-10), coalesced ----
__global__ __launch_bounds__(1024)
void kde_norm_kernel(const float* __restrict__ dpc, float* __restrict__ out)
{
    __shared__ float tile[MM][65];     // [m][nloc], odd stride
    __shared__ float rden[64];
    const int n0 = blockIdx.x * 64;
    const int t  = threadIdx.x;

    #pragma unroll
    for (int it = 0; it < 2; ++it) {
        const int m  = (t >> 4) + it * 64;
        const int nc = (t & 15) * 4;
        float4 v = *(const float4*)&dpc[(size_t)m * NN + n0 + nc];
        tile[m][nc]     = v.x;
        tile[m][nc + 1] = v.y;
        tile[m][nc + 2] = v.z;
        tile[m][nc + 3] = v.w;
    }
    __syncthreads();

    if (t < 64) {
        float s = 0.f;
        #pragma unroll 8
        for (int m = 0; m < MM; ++m) s += tile[m][t];
        rden[t] = 1.f / (s + 1e-10f);
    }
    __syncthreads();

    const int nloc = t >> 4;
    const int m0   = (t & 15) * 8;
    const float r  = rden[nloc];
    float4 o0, o1;
    o0.x = tile[m0][nloc] * r;     o0.y = tile[m0 + 1][nloc] * r;
    o0.z = tile[m0 + 2][nloc] * r; o0.w = tile[m0 + 3][nloc] * r;
    o1.x = tile[m0 + 4][nloc] * r; o1.y = tile[m0 + 5][nloc] * r;
    o1.z = tile[m0 + 6][nloc] * r; o1.w = tile[m0 + 7][nloc] * r;
    float* obase = &out[(size_t)(n0 + nloc) * MM + m0];
    *(float4*)obase       = o0;
    *(float4*)(obase + 4) = o1;
}

extern "C" void kernel_launch(void* const* d_in, const int* in_sizes, int n_in,
                              void* d_out, int out_size, void* d_ws, size_t ws_size,
                              hipStream_t stream) {
    const float* A   = (const float*)d_in[0];   // [4096][128]
    const float* B   = (const float*)d_in[1];   // [128][64][128] = [8192][128]
    const float* var = (const float*)d_in[2];   // [1]
    float* out = (float*)d_out;                 // [4096][128]

    unsigned char* A8 = (unsigned char*)d_ws;            // 512 KB
    unsigned char* B8 = A8 + (size_t)NN * DD;            // 1 MB
    float* a2  = (float*)(B8 + (size_t)CC * DD);         // 16 KB
    float* b2  = a2 + NN;                                // 32 KB
    float* dpc = b2 + CC;                                // 2 MB, [MM][NN]

    prep_kernel<<<(NN + CC) / 8, 256, 0, stream>>>(A, B, A8, B8, a2, b2);
    kde_dens_kernel<<<2048, 512, 0, stream>>>(A8, B8, var, a2, b2, dpc);
    kde_norm_kernel<<<NN / 64, 1024, 0, stream>>>(dpc, out);
}

// Round 12
// 78.328 us; speedup vs baseline: 3.3323x; 1.0050x over previous
//
#include <hip/hip_runtime.h>
#include <hip/hip_bf16.h>
#include <math.h>

// Problem constants (match reference setup_inputs)
#define NN 4096
#define MM 128
#define QQ 64
#define DD 128
#define CC (MM * QQ)          // 8192 gemm "columns" (flattened m,q)

typedef float f32x4 __attribute__((ext_vector_type(4)));
typedef int   i32x4 __attribute__((ext_vector_type(4)));
typedef int   i32x8 __attribute__((ext_vector_type(8)));

#define AS1 __attribute__((address_space(1)))
#define AS3 __attribute__((address_space(3)))

// ---- prep: fp32 -> fp8 e4m3 (OCP) convert + exact fp32 squared norms ----
__global__ __launch_bounds__(256)
void prep_kernel(const float* __restrict__ A, const float* __restrict__ B,
                 unsigned char* __restrict__ A8, unsigned char* __restrict__ B8,
                 float* __restrict__ a2, float* __restrict__ b2)
{
    const int row = blockIdx.x * 8 + (threadIdx.x >> 5);    // 0..12287
    const int l32 = threadIdx.x & 31;
    const float* src;
    unsigned char* dst;
    float* nrm;
    if (row < NN) { src = A + (size_t)row * DD; dst = A8 + (size_t)row * DD; nrm = a2 + row; }
    else {
        int r = row - NN;
        src = B + (size_t)r * DD; dst = B8 + (size_t)r * DD; nrm = b2 + r;
    }
    float4 v = ((const float4*)src)[l32];
    int pk = __builtin_amdgcn_cvt_pk_fp8_f32(v.x, v.y, 0, false);   // bytes 0,1
    pk     = __builtin_amdgcn_cvt_pk_fp8_f32(v.z, v.w, pk, true);   // bytes 2,3
    ((int*)dst)[l32] = pk;
    float s = v.x * v.x + v.y * v.y + v.z * v.z + v.w * v.w;
    #pragma unroll
    for (int m = 16; m > 0; m >>= 1) s += __shfl_xor(s, m, 64);  // stays in 32-group
    if (l32 == 0) *nrm = s;
}

// ---- dens: fp8 MX MFMA (K=128/instr), 128n x 128c per block, 64x64 WAVE tiles ----
// 4 waves of 256 threads: wave (wy=w>>1, wx=w&1) -> rows wy*64, cols wx*64 (one m).
// ds_read economy: (1/64+1/64) vs (1/32+1/64) -> 131K total b128 reads (-33% vs R11).
// LDS 33KB; __launch_bounds__(256,3) -> 12 waves/CU. XOR chunk swizzle as before.
__global__ __launch_bounds__(256, 3)
void kde_dens_kernel(const unsigned char* __restrict__ A8,   // [NN][DD] fp8
                     const unsigned char* __restrict__ B8,   // [CC][DD] fp8
                     const float* __restrict__ var,
                     const float* __restrict__ a2w,          // [NN]
                     const float* __restrict__ b2w,          // [CC]
                     float* __restrict__ dpc)                // [MM][NN] transposed
{
    __shared__ unsigned char As[128 * DD];   // 16 KB
    __shared__ unsigned char Bs[128 * DD];   // 16 KB
    __shared__ float a2s[128];
    __shared__ float b2s[128];
    __shared__ float red[4][64];

    // XCD swizzle: XCD x owns cb in [8x, 8x+8)
    const int lin = blockIdx.x;                 // 0..2047
    const int xcd = lin & 7;
    const int loc = lin >> 3;                   // 0..255
    const int cb  = (xcd << 3) | (loc & 7);     // 0..63
    const int nb  = loc >> 3;                   // 0..31
    const int n0  = nb * 128;
    const int c0  = cb * 128;

    const int t = threadIdx.x, w = t >> 6, lane = t & 63;

    // ---- async staging: 1024 A-chunks + 1024 B-chunks (16 B), 4+4 instrs/wave ----
    {
        const unsigned char* Ab = A8 + (size_t)n0 * DD;
        const unsigned char* Bb = B8 + (size_t)c0 * DD;
        #pragma unroll
        for (int i = 0; i < 4; ++i) {
            const int slot = w * 256 + i * 64 + lane;   // 0..1023
            const int r = slot >> 3, c16 = slot & 7, scb = c16 ^ (r & 7);
            __builtin_amdgcn_global_load_lds(
                (const AS1 unsigned int*)(Ab + r * DD + scb * 16),
                (AS3 unsigned int*)&As[slot * 16], 16, 0, 0);
            __builtin_amdgcn_global_load_lds(
                (const AS1 unsigned int*)(Bb + r * DD + scb * 16),
                (AS3 unsigned int*)&Bs[slot * 16], 16, 0, 0);
        }
        if (t < 128)        a2s[t]       = a2w[n0 + t];
        else                b2s[t - 128] = b2w[c0 + (t - 128)];
    }
    __syncthreads();   // drains vmcnt(0) incl. global_load_lds

    // ---- MFMA: wave (wy,wx) -> rows wy*64+[0,64), cols wx*64+[0,64) (one m) ----
    const int l15 = lane & 15, q = lane >> 4, xr = l15 & 7;
    const int wy = w >> 1, wx = w & 1;
    const int rbase = wy * 64, cbase = wx * 64;

    // A fragments: lane holds A[rbase+i*16+l15][q*32 .. q*32+31] (32 B = 2 b128)
    i32x8 a8[4];
    #pragma unroll
    for (int i = 0; i < 4; ++i) {
        const int ro = (rbase + i * 16 + l15) * DD;
        const i32x4 lo = *(const i32x4*)&As[ro + (((q << 1) | 0) ^ xr) * 16];
        const i32x4 hi = *(const i32x4*)&As[ro + (((q << 1) | 1) ^ xr) * 16];
        #pragma unroll
        for (int e = 0; e < 4; ++e) { a8[i][e] = lo[e]; a8[i][4 + e] = hi[e]; }
    }

    f32x4 acc[4][4] = {};
    #pragma unroll
    for (int j = 0; j < 4; ++j) {
        const int ro = (cbase + j * 16 + l15) * DD;
        const i32x4 lo = *(const i32x4*)&Bs[ro + (((q << 1) | 0) ^ xr) * 16];
        const i32x4 hi = *(const i32x4*)&Bs[ro + (((q << 1) | 1) ^ xr) * 16];
        i32x8 b8;
        #pragma unroll
        for (int e = 0; e < 4; ++e) { b8[e] = lo[e]; b8[4 + e] = hi[e]; }
        #pragma unroll
        for (int i = 0; i < 4; ++i)
            acc[i][j] = __builtin_amdgcn_mfma_scale_f32_16x16x128_f8f6f4(
                            a8[i], b8, acc[i][j],
                            0, 0,          // cbsz=0 (fp8 e4m3 A), blgp=0 (fp8 B)
                            0, 127,        // opsel_a, scale_a = E8M0 127 -> 1.0
                            0, 127);       // opsel_b, scale_b = 1.0
    }

    // ---- epilogue: dens = exp((2ab - a2 - b2) * 0.5/var); sum over 64 cols ----
    const float hinv = 0.5f / var[0];
    float rowsum[4][4];
    #pragma unroll
    for (int i = 0; i < 4; ++i) {
        #pragma unroll
        for (int reg = 0; reg < 4; ++reg) {
            const float a2 = a2s[rbase + i * 16 + q * 4 + reg];
            float p = 0.f;
            #pragma unroll
            for (int j = 0; j < 4; ++j) {
                const float b2 = b2s[cbase + j * 16 + l15];
                p += __expf((2.f * acc[i][j][reg] - a2 - b2) * hinv);
            }
            rowsum[i][reg] = p;
        }
    }
    #pragma unroll
    for (int mask = 1; mask < 16; mask <<= 1)
        #pragma unroll
        for (int i = 0; i < 4; ++i)
            #pragma unroll
            for (int reg = 0; reg < 4; ++reg)
                rowsum[i][reg] += __shfl_xor(rowsum[i][reg], mask, 64);

    // coalesce via wave-private LDS slot (in-order LDS pipe, no barrier needed):
    // 4 lanes (l15==0, q=0..3) write 4x f32x4 each -> red[w][0..64)
    if (l15 == 0) {
        #pragma unroll
        for (int i = 0; i < 4; ++i) {
            f32x4 o = {rowsum[i][0], rowsum[i][1], rowsum[i][2], rowsum[i][3]};
            *(f32x4*)&red[w][i * 16 + q * 4] = o;
        }
    }
    const int m = (cb << 1) + wx;
    dpc[(size_t)m * NN + n0 + rbase + lane] = red[w][lane];  // 256B/wave, coalesced
}

// ---- normalize: out[n,m] = dpc[m,n] / (sum_m dpc[:,n] + 1e-10), coalesced ----
__global__ __launch_bounds__(1024)
void kde_norm_kernel(const float* __restrict__ dpc, float* __restrict__ out)
{
    __shared__ float tile[MM][65];     // [m][nloc], odd stride
    __shared__ float rden[64];
    const int n0 = blockIdx.x * 64;
    const int t  = threadIdx.x;

    #pragma unroll
    for (int it = 0; it < 2; ++it) {
        const int m  = (t >> 4) + it * 64;
        const int nc = (t & 15) * 4;
        float4 v = *(const float4*)&dpc[(size_t)m * NN + n0 + nc];
        tile[m][nc]     = v.x;
        tile[m][nc + 1] = v.y;
        tile[m][nc + 2] = v.z;
        tile[m][nc + 3] = v.w;
    }
    __syncthreads();

    if (t < 64) {
        float s = 0.f;
        #pragma unroll 8
        for (int m = 0; m < MM; ++m) s += tile[m][t];
        rden[t] = 1.f / (s + 1e-10f);
    }
    __syncthreads();

    const int nloc = t >> 4;
    const int m0   = (t & 15) * 8;
    const float r  = rden[nloc];
    float4 o0, o1;
    o0.x = tile[m0][nloc] * r;     o0.y = tile[m0 + 1][nloc] * r;
    o0.z = tile[m0 + 2][nloc] * r; o0.w = tile[m0 + 3][nloc] * r;
    o1.x = tile[m0 + 4][nloc] * r; o1.y = tile[m0 + 5][nloc] * r;
    o1.z = tile[m0 + 6][nloc] * r; o1.w = tile[m0 + 7][nloc] * r;
    float* obase = &out[(size_t)(n0 + nloc) * MM + m0];
    *(float4*)obase       = o0;
    *(float4*)(obase + 4) = o1;
}

extern "C" void kernel_launch(void* const* d_in, const int* in_sizes, int n_in,
                              void* d_out, int out_size, void* d_ws, size_t ws_size,
                              hipStream_t stream) {
    const float* A   = (const float*)d_in[0];   // [4096][128]
    const float* B   = (const float*)d_in[1];   // [128][64][128] = [8192][128]
    const float* var = (const float*)d_in[2];   // [1]
    float* out = (float*)d_out;                 // [4096][128]

    unsigned char* A8 = (unsigned char*)d_ws;            // 512 KB
    unsigned char* B8 = A8 + (size_t)NN * DD;            // 1 MB
    float* a2  = (float*)(B8 + (size_t)CC * DD);         // 16 KB
    float* b2  = a2 + NN;                                // 32 KB
    float* dpc = b2 + CC;                                // 2 MB, [MM][NN]

    prep_kernel<<<(NN + CC) / 8, 256, 0, stream>>>(A, B, A8, B8, a2, b2);
    kde_dens_kernel<<<2048, 256, 0, stream>>>(A8, B8, var, a2, b2, dpc);
    kde_norm_kernel<<<NN / 64, 1024, 0, stream>>>(dpc, out);
}